// Round 5
// baseline (184.330 us; speedup 1.0000x reference)
//
#include <hip/hip_runtime.h>
#include <hip/hip_fp16.h>

#define NG 64
#define NVOX (NG*NG*NG)
#define NC 16
#define NHID 32
#define NL 10
#define NBINS 32768          // 32^3 cells, 2^3 voxels each

typedef _Float16 half8 __attribute__((ext_vector_type(8)));
typedef __fp16   fp16x2 __attribute__((ext_vector_type(2)));
typedef float f32x16 __attribute__((ext_vector_type(16)));

union U32H2 { unsigned u; fp16x2 h; __half2 hh; };

__device__ __forceinline__ unsigned pkrtz(float a, float b) {
    U32H2 t; t.h = __builtin_amdgcn_cvt_pkrtz(a, b); return t.u;
}
__device__ __forceinline__ half8 mk8(unsigned a, unsigned b, unsigned c, unsigned d) {
    union { unsigned u[4]; half8 v; } r;
    r.u[0] = a; r.u[1] = b; r.u[2] = c; r.u[3] = d; return r.v;
}
__device__ __forceinline__ f32x16 MF(half8 a, half8 b, f32x16 c) {
    return __builtin_amdgcn_mfma_f32_32x32x16_f16(a, b, c, 0, 0, 0);
}
__device__ __forceinline__ unsigned hfma2u(unsigned a, unsigned b, unsigned c) {
    U32H2 A, B, C, R; A.u = a; B.u = b; C.u = c;
    R.hh = __hfma2(A.hh, B.hh, C.hh); return R.u;
}
#define PSWAP(a, b) asm volatile("v_permlane32_swap_b32 %0, %1" : "+v"(a), "+v"(b))

__device__ __forceinline__ int cell_of(float cx, float cy, float cz) {
    int bx = min(max((int)((cx + 1.0f) * 16.0f), 0), 31);
    int by = min(max((int)((cy + 1.0f) * 16.0f), 0), 31);
    int bz = min(max((int)((cz + 1.0f) * 16.0f), 0), 31);
    return (bz * 32 + by) * 32 + bx;
}

// ---- workspace layout ----
#define GRID_BYTES ((size_t)NVOX * NC * 2)            // 8 MiB f16 voxel-major grid
#define HIST_OFF   GRID_BYTES
#define CURS_OFF   (HIST_OFF + (size_t)NBINS * 4)
#define SORT_OFF   (CURS_OFF + (size_t)NBINS * 4)     // + n*16 bytes

// ---- pass 1: grid (C,D,H,W) f32 -> voxel-major f16 ----
__global__ __launch_bounds__(256) void grid_to_h16(const float* __restrict__ in,
                                                   unsigned* __restrict__ out)
{
    int v = blockIdx.x * 256 + threadIdx.x;
    if (v >= NVOX) return;
    unsigned o[8];
#pragma unroll
    for (int c = 0; c < 8; ++c) {
        float a = in[(2 * c) * NVOX + v];
        float b = in[(2 * c + 1) * NVOX + v];
        U32H2 t; t.hh = __floats2half2_rn(a, b); o[c] = t.u;
    }
    uint4* dst = reinterpret_cast<uint4*>(out + (size_t)v * 8);
    dst[0] = make_uint4(o[0], o[1], o[2], o[3]);
    dst[1] = make_uint4(o[4], o[5], o[6], o[7]);
}

// ---- sort pass A: histogram ----
__global__ __launch_bounds__(256) void hist_kernel(const float* __restrict__ coords,
                                                   unsigned* __restrict__ hist, int n)
{
    int i = blockIdx.x * 256 + threadIdx.x;
    if (i >= n) return;
    atomicAdd(&hist[cell_of(coords[3 * i], coords[3 * i + 1], coords[3 * i + 2])], 1u);
}

// ---- sort pass B: exclusive scan of 32768 bins, one block ----
__global__ __launch_bounds__(1024) void scan_kernel(const unsigned* __restrict__ hist,
                                                    unsigned* __restrict__ cursor)
{
    __shared__ unsigned ps[1024];
    int t = threadIdx.x;
    unsigned loc[32], s = 0;
#pragma unroll
    for (int i = 0; i < 32; ++i) { loc[i] = s; s += hist[t * 32 + i]; }
    ps[t] = s;
    __syncthreads();
    for (int off = 1; off < 1024; off <<= 1) {
        unsigned v = (t >= off) ? ps[t - off] : 0u;
        __syncthreads();
        ps[t] += v;
        __syncthreads();
    }
    unsigned base = (t == 0) ? 0u : ps[t - 1];
#pragma unroll
    for (int i = 0; i < 32; ++i) cursor[t * 32 + i] = base + loc[i];
}

// ---- sort pass C: scatter coords+idx into bin order ----
__global__ __launch_bounds__(256) void scatter_kernel(const float* __restrict__ coords,
                                                      unsigned* __restrict__ cursor,
                                                      uint4* __restrict__ sorted, int n)
{
    int i = blockIdx.x * 256 + threadIdx.x;
    if (i >= n) return;
    float cx = coords[3 * i], cy = coords[3 * i + 1], cz = coords[3 * i + 2];
    unsigned pos = atomicAdd(&cursor[cell_of(cx, cy, cz)], 1u);
    sorted[pos] = make_uint4(__float_as_uint(cx), __float_as_uint(cy),
                             __float_as_uint(cz), (unsigned)i);
}

// ---- main: fused grid-sample + PE + 4-layer MLP, f16 MFMA (R3 body) ----
template<bool SORTED>
__global__ __launch_bounds__(256) void fgm_mfma(
    const float* __restrict__ coords, const uint4* __restrict__ sorted,
    const unsigned* __restrict__ gridh,
    const float* __restrict__ W0, const float* __restrict__ b0,
    const float* __restrict__ Wh, const float* __restrict__ bh,
    const float* __restrict__ Wf, const float* __restrict__ bf,
    float* __restrict__ out, int n)
{
    __shared__ unsigned lds[4][40 * 64];
    // bijective XCD swizzle: contiguous sorted chunks per XCD (m204 formula)
    int nwg = gridDim.x;
    int q = nwg >> 3, r = nwg & 7;
    int xcd = blockIdx.x & 7, idx = blockIdx.x >> 3;
    int wg = (xcd < r ? xcd * (q + 1) : r * (q + 1) + (xcd - r) * q) + idx;

    const int lane = threadIdx.x & 63;
    const int wid  = threadIdx.x >> 6;
    const int base = wg * 256 + wid * 64;
    if (base >= n) return;
    const int p  = base + lane;
    const int pc = min(p, n - 1);
    const int H  = lane >> 5;
    const int m  = lane & 31;
    const int nn = m;
    unsigned* myl = lds[wid];

    float cx, cy, cz; unsigned oi;
    if (SORTED) {
        uint4 sq = sorted[pc];
        cx = __uint_as_float(sq.x); cy = __uint_as_float(sq.y);
        cz = __uint_as_float(sq.z); oi = sq.w;
    } else {
        cx = coords[3 * pc + 0]; cy = coords[3 * pc + 1]; cz = coords[3 * pc + 2];
        oi = (unsigned)pc;
    }

    // ---- A-fragments for layer 0 (k-permuted W0 rows; k=3 is the bias row) ----
    half8 a0[5];
#pragma unroll
    for (int s = 0; s < 5; ++s) {
        float e[8];
#pragma unroll
        for (int i = 0; i < 8; ++i) {
            const int k0 = s * 16 + i;
            const float* q0 = (k0 == 3) ? (b0 + nn)
                             : (W0 + (k0 - (k0 >= 4 ? 1 : 0)) * NHID + nn);
            const float* q1 = W0 + (k0 + 8 - 1) * NHID + nn;
            e[i] = *(H ? q1 : q0);
        }
        a0[s] = mk8(pkrtz(e[0], e[1]), pkrtz(e[2], e[3]),
                    pkrtz(e[4], e[5]), pkrtz(e[6], e[7]));
    }

    // ---- trilinear grid sample, packed f16 ----
    float fx = (cx + 1.0f) * (NG * 0.5f) - 0.5f;
    float fy = (cy + 1.0f) * (NG * 0.5f) - 0.5f;
    float fz = (cz + 1.0f) * (NG * 0.5f) - 0.5f;
    float flx = floorf(fx), fly = floorf(fy), flz = floorf(fz);
    float wx = fx - flx, wy = fy - fly, wz = fz - flz;
    int ix0 = (int)flx, iy0 = (int)fly, iz0 = (int)flz;
    float wxs[2] = {1.0f - wx, wx}, wys[2] = {1.0f - wy, wy}, wzs[2] = {1.0f - wz, wz};

    unsigned fvp[8];
#pragma unroll
    for (int j = 0; j < 8; ++j) fvp[j] = 0u;

#pragma unroll
    for (int dz = 0; dz < 2; ++dz) {
        int zi = iz0 + dz; bool vz = (zi >= 0) && (zi < NG);
        int zc = min(max(zi, 0), NG - 1);
#pragma unroll
        for (int dy = 0; dy < 2; ++dy) {
            int yi = iy0 + dy; bool vy = (yi >= 0) && (yi < NG);
            int yc = min(max(yi, 0), NG - 1);
#pragma unroll
            for (int dx = 0; dx < 2; ++dx) {
                int xi = ix0 + dx; bool vx = (xi >= 0) && (xi < NG);
                int xc = min(max(xi, 0), NG - 1);
                float w = wzs[dz] * wys[dy] * wxs[dx];
                w = (vx && vy && vz) ? w : 0.0f;
                U32H2 w2; w2.hh = __float2half2_rn(w);
                const uint4* g = reinterpret_cast<const uint4*>(
                    gridh + (size_t)(((zc * NG) + yc) * NG + xc) * 8);
                uint4 qa = g[0], qb = g[1];
                fvp[0] = hfma2u(qa.x, w2.u, fvp[0]);
                fvp[1] = hfma2u(qa.y, w2.u, fvp[1]);
                fvp[2] = hfma2u(qa.z, w2.u, fvp[2]);
                fvp[3] = hfma2u(qa.w, w2.u, fvp[3]);
                fvp[4] = hfma2u(qb.x, w2.u, fvp[4]);
                fvp[5] = hfma2u(qb.y, w2.u, fvp[5]);
                fvp[6] = hfma2u(qb.z, w2.u, fvp[6]);
                fvp[7] = hfma2u(qb.w, w2.u, fvp[7]);
            }
        }
    }

    // ---- write x (f16 pairs) into this wave's LDS slab ----
    myl[0 * 64 + lane] = pkrtz(cx, cy);
    myl[1 * 64 + lane] = pkrtz(cz, 1.0f);
#pragma unroll
    for (int l0 = 0; l0 < NL; ++l0) {
        float f = (float)(1 << l0);
        float sx, cax, sy, cay, sz, caz;
        __sincosf(cx * f, &sx, &cax);
        __sincosf(cy * f, &sy, &cay);
        __sincosf(cz * f, &sz, &caz);
        myl[(2 + 3 * l0 + 0) * 64 + lane] = pkrtz(sx, sy);
        myl[(2 + 3 * l0 + 1) * 64 + lane] = pkrtz(sz, cax);
        myl[(2 + 3 * l0 + 2) * 64 + lane] = pkrtz(cay, caz);
    }
#pragma unroll
    for (int j = 0; j < 8; ++j) myl[(32 + j) * 64 + lane] = fvp[j];

    asm volatile("s_waitcnt lgkmcnt(0)" ::: "memory");

    // ---- layer 0: 5 K-slices x 2 tiles ----
    f32x16 acc0, acc1;
#pragma unroll
    for (int r2 = 0; r2 < 16; ++r2) { acc0[r2] = 0.0f; acc1[r2] = 0.0f; }
#pragma unroll
    for (int s = 0; s < 5; ++s) {
        unsigned bw0[4], bw1[4];
#pragma unroll
        for (int j = 0; j < 4; ++j) {
            int row = s * 8 + H * 4 + j;
            bw0[j] = myl[row * 64 + m];
            bw1[j] = myl[row * 64 + 32 + m];
        }
        acc0 = MF(a0[s], mk8(bw0[0], bw0[1], bw0[2], bw0[3]), acc0);
        acc1 = MF(a0[s], mk8(bw1[0], bw1[1], bw1[2], bw1[3]), acc1);
    }

    // ---- hidden layers ----
#pragma unroll
    for (int L = 0; L < 3; ++L) {
        unsigned w0a[8], w1a[8];
#pragma unroll
        for (int j = 0; j < 8; ++j) {
            {
                float x0 = acc0[2 * j], x1 = acc0[2 * j + 1];
                float s0 = __sinf(x0), s1 = __sinf(x1);
                w0a[j] = pkrtz(fmaf(0.5f, x0, s0 * s0), fmaf(0.5f, x1, s1 * s1));
            }
            {
                float x0 = acc1[2 * j], x1 = acc1[2 * j + 1];
                float s0 = __sinf(x0), s1 = __sinf(x1);
                w1a[j] = pkrtz(fmaf(0.5f, x0, s0 * s0), fmaf(0.5f, x1, s1 * s1));
            }
        }
        PSWAP(w0a[0], w0a[2]); PSWAP(w0a[1], w0a[3]);
        PSWAP(w0a[4], w0a[6]); PSWAP(w0a[5], w0a[7]);
        PSWAP(w1a[0], w1a[2]); PSWAP(w1a[1], w1a[3]);
        PSWAP(w1a[4], w1a[6]); PSWAP(w1a[5], w1a[7]);

        f32x16 cb;
#pragma unroll
        for (int r2 = 0; r2 < 16; ++r2) {
            int nr = (r2 & 3) + 8 * (r2 >> 2) + 4 * H;
            cb[r2] = bh[L * NHID + nr];
        }
        half8 ah0, ah1;
        {
            float e[8];
#pragma unroll
            for (int i = 0; i < 8; ++i) e[i] = Wh[(L * NHID + H * 8 + i) * NHID + nn];
            ah0 = mk8(pkrtz(e[0], e[1]), pkrtz(e[2], e[3]),
                      pkrtz(e[4], e[5]), pkrtz(e[6], e[7]));
        }
        {
            float e[8];
#pragma unroll
            for (int i = 0; i < 8; ++i) e[i] = Wh[(L * NHID + 16 + H * 8 + i) * NHID + nn];
            ah1 = mk8(pkrtz(e[0], e[1]), pkrtz(e[2], e[3]),
                      pkrtz(e[4], e[5]), pkrtz(e[6], e[7]));
        }
        acc0 = MF(ah1, mk8(w0a[4], w0a[5], w0a[6], w0a[7]),
                  MF(ah0, mk8(w0a[0], w0a[1], w0a[2], w0a[3]), cb));
        acc1 = MF(ah1, mk8(w1a[4], w1a[5], w1a[6], w1a[7]),
                  MF(ah0, mk8(w1a[0], w1a[1], w1a[2], w1a[3]), cb));
    }

    // ---- final layer ----
    float t0 = 0.0f, t1 = 0.0f;
#pragma unroll
    for (int r2 = 0; r2 < 16; ++r2) {
        int nr = (r2 & 3) + 8 * (r2 >> 2) + 4 * H;
        float wf = Wf[nr];
        { float x = acc0[r2]; float s = __sinf(x); t0 = fmaf(fmaf(0.5f, x, s * s), wf, t0); }
        { float x = acc1[r2]; float s = __sinf(x); t1 = fmaf(fmaf(0.5f, x, s * s), wf, t1); }
    }
    t0 += __shfl_xor(t0, 32);
    t1 += __shfl_xor(t1, 32);
    float res = (H ? t1 : t0) + bf[0];
    if (p < n) out[oi] = res;
}

// ---- fallback (tiny ws): scalar fp32 path ----
__global__ __launch_bounds__(256) void fgm_scalar(
    const float* __restrict__ coords, const float* __restrict__ grid,
    const float* __restrict__ W0, const float* __restrict__ b0,
    const float* __restrict__ Wh, const float* __restrict__ bh,
    const float* __restrict__ Wf, const float* __restrict__ bf,
    float* __restrict__ out, int n)
{
    int i = blockIdx.x * blockDim.x + threadIdx.x;
    if (i >= n) return;
    float cx = coords[3 * i + 0], cy = coords[3 * i + 1], cz = coords[3 * i + 2];
    float fx = (cx + 1.0f) * (NG * 0.5f) - 0.5f;
    float fy = (cy + 1.0f) * (NG * 0.5f) - 0.5f;
    float fz = (cz + 1.0f) * (NG * 0.5f) - 0.5f;
    float flx = floorf(fx), fly = floorf(fy), flz = floorf(fz);
    float wx = fx - flx, wy = fy - fly, wz = fz - flz;
    int ix0 = (int)flx, iy0 = (int)fly, iz0 = (int)flz;
    float fv[NC];
#pragma unroll
    for (int c = 0; c < NC; ++c) fv[c] = 0.0f;
    float wxs[2] = {1.0f - wx, wx}, wys[2] = {1.0f - wy, wy}, wzs[2] = {1.0f - wz, wz};
#pragma unroll
    for (int dz = 0; dz < 2; ++dz) {
        int zi = iz0 + dz; bool vz = (zi >= 0) && (zi < NG);
        int zc = min(max(zi, 0), NG - 1);
#pragma unroll
        for (int dy = 0; dy < 2; ++dy) {
            int yi = iy0 + dy; bool vy = (yi >= 0) && (yi < NG);
            int yc = min(max(yi, 0), NG - 1);
#pragma unroll
            for (int dx = 0; dx < 2; ++dx) {
                int xi = ix0 + dx; bool vx = (xi >= 0) && (xi < NG);
                int xc = min(max(xi, 0), NG - 1);
                float w = wzs[dz] * wys[dy] * wxs[dx];
                w = (vx && vy && vz) ? w : 0.0f;
                int off = ((zc * NG) + yc) * NG + xc;
#pragma unroll
                for (int c = 0; c < NC; ++c)
                    fv[c] = fmaf(w, grid[c * NVOX + off], fv[c]);
            }
        }
    }
    float h[NHID];
#pragma unroll
    for (int j = 0; j < NHID; ++j) h[j] = b0[j];
#pragma unroll
    for (int j = 0; j < NHID; ++j) h[j] = fmaf(cx, W0[0 * NHID + j], h[j]);
#pragma unroll
    for (int j = 0; j < NHID; ++j) h[j] = fmaf(cy, W0[1 * NHID + j], h[j]);
#pragma unroll
    for (int j = 0; j < NHID; ++j) h[j] = fmaf(cz, W0[2 * NHID + j], h[j]);
#pragma unroll
    for (int l = 0; l < NL; ++l) {
        float fs = (float)(1 << l);
        float sv[6];
        sv[0] = __sinf(cx * fs); sv[1] = __sinf(cy * fs); sv[2] = __sinf(cz * fs);
        sv[3] = __cosf(cx * fs); sv[4] = __cosf(cy * fs); sv[5] = __cosf(cz * fs);
#pragma unroll
        for (int r = 0; r < 6; ++r) {
            const float* wr = W0 + (size_t)(3 + 6 * l + r) * NHID;
            float a = sv[r];
#pragma unroll
            for (int j = 0; j < NHID; ++j) h[j] = fmaf(a, wr[j], h[j]);
        }
    }
#pragma unroll
    for (int r = 0; r < NC; ++r) {
        const float* wr = W0 + (size_t)(3 + 6 * NL + r) * NHID;
        float a = fv[r];
#pragma unroll
        for (int j = 0; j < NHID; ++j) h[j] = fmaf(a, wr[j], h[j]);
    }
    float act[NHID];
#pragma unroll
    for (int layer = 0; layer < 3; ++layer) {
#pragma unroll
        for (int j = 0; j < NHID; ++j) {
            float s = __sinf(h[j]);
            act[j] = fmaf(0.5f, h[j], s * s);
        }
#pragma unroll
        for (int j = 0; j < NHID; ++j) h[j] = bh[layer * NHID + j];
#pragma unroll
        for (int r = 0; r < NHID; ++r) {
            const float* wr = Wh + (size_t)(layer * NHID + r) * NHID;
            float a = act[r];
#pragma unroll
            for (int j = 0; j < NHID; ++j) h[j] = fmaf(a, wr[j], h[j]);
        }
    }
    float acc = bf[0];
#pragma unroll
    for (int j = 0; j < NHID; ++j) {
        float s = __sinf(h[j]);
        acc = fmaf(fmaf(0.5f, h[j], s * s), Wf[j], acc);
    }
    out[i] = acc;
}

extern "C" void kernel_launch(void* const* d_in, const int* in_sizes, int n_in,
                              void* d_out, int out_size, void* d_ws, size_t ws_size,
                              hipStream_t stream)
{
    const float* coords = (const float*)d_in[0];
    const float* grid   = (const float*)d_in[1];
    const float* W0     = (const float*)d_in[2];
    const float* b0     = (const float*)d_in[3];
    const float* Wh     = (const float*)d_in[4];
    const float* bh     = (const float*)d_in[5];
    const float* Wf     = (const float*)d_in[6];
    const float* bf     = (const float*)d_in[7];
    float* out = (float*)d_out;
    int n = in_sizes[0] / 3;
    int nblk = (n + 255) / 256;

    size_t sort_need = SORT_OFF + (size_t)n * 16;
    if (ws_size >= sort_need) {
        char* ws = (char*)d_ws;
        unsigned* gh     = (unsigned*)ws;
        unsigned* hist   = (unsigned*)(ws + HIST_OFF);
        unsigned* cursor = (unsigned*)(ws + CURS_OFF);
        uint4*    sorted = (uint4*)(ws + SORT_OFF);
        grid_to_h16<<<(NVOX + 255) / 256, 256, 0, stream>>>(grid, gh);
        hipMemsetAsync(hist, 0, (size_t)NBINS * 4, stream);
        hist_kernel<<<nblk, 256, 0, stream>>>(coords, hist, n);
        scan_kernel<<<1, 1024, 0, stream>>>(hist, cursor);
        scatter_kernel<<<nblk, 256, 0, stream>>>(coords, cursor, sorted, n);
        fgm_mfma<true><<<nblk, 256, 0, stream>>>(
            coords, sorted, gh, W0, b0, Wh, bh, Wf, bf, out, n);
    } else if (ws_size >= GRID_BYTES) {
        unsigned* gh = (unsigned*)d_ws;
        grid_to_h16<<<(NVOX + 255) / 256, 256, 0, stream>>>(grid, gh);
        fgm_mfma<false><<<nblk, 256, 0, stream>>>(
            coords, (const uint4*)nullptr, gh, W0, b0, Wh, bh, Wf, bf, out, n);
    } else {
        fgm_scalar<<<nblk, 256, 0, stream>>>(
            coords, grid, W0, b0, Wh, bh, Wf, bf, out, n);
    }
}

// Round 6
// 81.283 us; speedup vs baseline: 2.2677x; 2.2677x over previous
//
#include <hip/hip_runtime.h>
#include <hip/hip_fp16.h>

#define NG 64
#define NVOX (NG*NG*NG)
#define NC 16
#define NHID 32
#define NL 10

typedef _Float16 half8 __attribute__((ext_vector_type(8)));
typedef __fp16   fp16x2 __attribute__((ext_vector_type(2)));
typedef float f32x16 __attribute__((ext_vector_type(16)));
typedef float f32x2 __attribute__((ext_vector_type(2)));

union U32H2 { unsigned u; fp16x2 h; __half2 hh; };

__device__ __forceinline__ unsigned pkrtz(float a, float b) {
    U32H2 t; t.h = __builtin_amdgcn_cvt_pkrtz(a, b); return t.u;
}
__device__ __forceinline__ half8 mk8(unsigned a, unsigned b, unsigned c, unsigned d) {
    union { unsigned u[4]; half8 v; } r;
    r.u[0] = a; r.u[1] = b; r.u[2] = c; r.u[3] = d; return r.v;
}
__device__ __forceinline__ f32x16 MF(half8 a, half8 b, f32x16 c) {
    return __builtin_amdgcn_mfma_f32_32x32x16_f16(a, b, c, 0, 0, 0);
}
#define PSWAP(a, b) asm volatile("v_permlane32_swap_b32 %0, %1" : "+v"(a), "+v"(b))

// ---- pass 1: grid (C,D,H,W) f32 -> voxel-major fp8 e4m3 (D,H,W,C), 4 MiB ----
__global__ __launch_bounds__(256) void grid_to_fp8(const float* __restrict__ in,
                                                   uint4* __restrict__ out)
{
    int v = blockIdx.x * 256 + threadIdx.x;
    if (v >= NVOX) return;
    unsigned o[4];
#pragma unroll
    for (int c = 0; c < 4; ++c) {
        float f0 = in[(4 * c + 0) * NVOX + v];
        float f1 = in[(4 * c + 1) * NVOX + v];
        float f2 = in[(4 * c + 2) * NVOX + v];
        float f3 = in[(4 * c + 3) * NVOX + v];
        int w = 0;
        w = __builtin_amdgcn_cvt_pk_fp8_f32(f0, f1, w, false);  // bytes 0,1
        w = __builtin_amdgcn_cvt_pk_fp8_f32(f2, f3, w, true);   // bytes 2,3
        o[c] = (unsigned)w;
    }
    out[v] = make_uint4(o[0], o[1], o[2], o[3]);
}

// ---- pass 2: fused grid-sample + PE + 4-layer MLP, f16 MFMA (R3 body) ----
// Wave = 64 points = 2 MFMA m-tiles of 32. x layout (k-permuted, 80 rows):
// k0..1=cx,cy  k2=cz  k3=1(bias row->b0)  k4..63=PE  k64..79=feats.
// D: col=lane&31, row=(r&3)+8*(r>>2)+4*(lane>>5).
__global__ __launch_bounds__(256) void fgm_mfma(
    const float* __restrict__ coords, const uint4* __restrict__ grid8,
    const float* __restrict__ W0, const float* __restrict__ b0,
    const float* __restrict__ Wh, const float* __restrict__ bh,
    const float* __restrict__ Wf, const float* __restrict__ bf,
    float* __restrict__ out, int n)
{
    __shared__ unsigned lds[4][40 * 64];   // per-wave slab: 40 half2-rows x 64 pts
    const int lane = threadIdx.x & 63;
    const int wid  = threadIdx.x >> 6;
    const int base = blockIdx.x * 256 + wid * 64;
    if (base >= n) return;
    const int p  = base + lane;
    const int pc = min(p, n - 1);
    const int H  = lane >> 5;
    const int m  = lane & 31;
    const int nn = m;
    unsigned* myl = lds[wid];

    float cx = coords[3 * pc + 0], cy = coords[3 * pc + 1], cz = coords[3 * pc + 2];

    // ---- A-fragments for layer 0 (k-permuted W0 rows; k=3 is the bias row) ----
    half8 a0[5];
#pragma unroll
    for (int s = 0; s < 5; ++s) {
        float e[8];
#pragma unroll
        for (int i = 0; i < 8; ++i) {
            const int k0 = s * 16 + i;
            const float* q0 = (k0 == 3) ? (b0 + nn)
                             : (W0 + (k0 - (k0 >= 4 ? 1 : 0)) * NHID + nn);
            const float* q1 = W0 + (k0 + 8 - 1) * NHID + nn;   // k1>=8, never bias
            e[i] = *(H ? q1 : q0);
        }
        a0[s] = mk8(pkrtz(e[0], e[1]), pkrtz(e[2], e[3]),
                    pkrtz(e[4], e[5]), pkrtz(e[6], e[7]));
    }

    // ---- trilinear grid sample, fp8 grid -> f32 accumulate ----
    float fx = (cx + 1.0f) * (NG * 0.5f) - 0.5f;
    float fy = (cy + 1.0f) * (NG * 0.5f) - 0.5f;
    float fz = (cz + 1.0f) * (NG * 0.5f) - 0.5f;
    float flx = floorf(fx), fly = floorf(fy), flz = floorf(fz);
    float wx = fx - flx, wy = fy - fly, wz = fz - flz;
    int ix0 = (int)flx, iy0 = (int)fly, iz0 = (int)flz;
    float wxs[2] = {1.0f - wx, wx}, wys[2] = {1.0f - wy, wy}, wzs[2] = {1.0f - wz, wz};

    float fv[NC];
#pragma unroll
    for (int c = 0; c < NC; ++c) fv[c] = 0.0f;

#pragma unroll
    for (int dz = 0; dz < 2; ++dz) {
        int zi = iz0 + dz; bool vz = (zi >= 0) && (zi < NG);
        int zc = min(max(zi, 0), NG - 1);
#pragma unroll
        for (int dy = 0; dy < 2; ++dy) {
            int yi = iy0 + dy; bool vy = (yi >= 0) && (yi < NG);
            int yc = min(max(yi, 0), NG - 1);
#pragma unroll
            for (int dx = 0; dx < 2; ++dx) {
                int xi = ix0 + dx; bool vx = (xi >= 0) && (xi < NG);
                int xc = min(max(xi, 0), NG - 1);
                float w = wzs[dz] * wys[dy] * wxs[dx];
                w = (vx && vy && vz) ? w : 0.0f;
                uint4 q = grid8[((zc * NG) + yc) * NG + xc];
                f32x2 d;
                d = __builtin_amdgcn_cvt_pk_f32_fp8((int)q.x, false);
                fv[0]  = fmaf(w, d.x, fv[0]);  fv[1]  = fmaf(w, d.y, fv[1]);
                d = __builtin_amdgcn_cvt_pk_f32_fp8((int)q.x, true);
                fv[2]  = fmaf(w, d.x, fv[2]);  fv[3]  = fmaf(w, d.y, fv[3]);
                d = __builtin_amdgcn_cvt_pk_f32_fp8((int)q.y, false);
                fv[4]  = fmaf(w, d.x, fv[4]);  fv[5]  = fmaf(w, d.y, fv[5]);
                d = __builtin_amdgcn_cvt_pk_f32_fp8((int)q.y, true);
                fv[6]  = fmaf(w, d.x, fv[6]);  fv[7]  = fmaf(w, d.y, fv[7]);
                d = __builtin_amdgcn_cvt_pk_f32_fp8((int)q.z, false);
                fv[8]  = fmaf(w, d.x, fv[8]);  fv[9]  = fmaf(w, d.y, fv[9]);
                d = __builtin_amdgcn_cvt_pk_f32_fp8((int)q.z, true);
                fv[10] = fmaf(w, d.x, fv[10]); fv[11] = fmaf(w, d.y, fv[11]);
                d = __builtin_amdgcn_cvt_pk_f32_fp8((int)q.w, false);
                fv[12] = fmaf(w, d.x, fv[12]); fv[13] = fmaf(w, d.y, fv[13]);
                d = __builtin_amdgcn_cvt_pk_f32_fp8((int)q.w, true);
                fv[14] = fmaf(w, d.x, fv[14]); fv[15] = fmaf(w, d.y, fv[15]);
            }
        }
    }

    // ---- write x (f16 pairs) into this wave's LDS slab ----
    myl[0 * 64 + lane] = pkrtz(cx, cy);
    myl[1 * 64 + lane] = pkrtz(cz, 1.0f);      // k=3: bias row input = 1
#pragma unroll
    for (int l0 = 0; l0 < NL; ++l0) {
        float f = (float)(1 << l0);
        float sx, cax, sy, cay, sz, caz;
        __sincosf(cx * f, &sx, &cax);
        __sincosf(cy * f, &sy, &cay);
        __sincosf(cz * f, &sz, &caz);
        myl[(2 + 3 * l0 + 0) * 64 + lane] = pkrtz(sx, sy);
        myl[(2 + 3 * l0 + 1) * 64 + lane] = pkrtz(sz, cax);
        myl[(2 + 3 * l0 + 2) * 64 + lane] = pkrtz(cay, caz);
    }
#pragma unroll
    for (int j = 0; j < 8; ++j)
        myl[(32 + j) * 64 + lane] = pkrtz(fv[2 * j], fv[2 * j + 1]);

    asm volatile("s_waitcnt lgkmcnt(0)" ::: "memory");  // wave-local LDS RAW

    // ---- layer 0: 5 K-slices x 2 tiles ----
    f32x16 acc0, acc1;
#pragma unroll
    for (int r = 0; r < 16; ++r) { acc0[r] = 0.0f; acc1[r] = 0.0f; }
#pragma unroll
    for (int s = 0; s < 5; ++s) {
        unsigned bw0[4], bw1[4];
#pragma unroll
        for (int j = 0; j < 4; ++j) {
            int row = s * 8 + H * 4 + j;
            bw0[j] = myl[row * 64 + m];
            bw1[j] = myl[row * 64 + 32 + m];
        }
        acc0 = MF(a0[s], mk8(bw0[0], bw0[1], bw0[2], bw0[3]), acc0);
        acc1 = MF(a0[s], mk8(bw1[0], bw1[1], bw1[2], bw1[3]), acc1);
    }

    // ---- hidden layers: snake -> f16 pairs -> permlane B-frags -> MFMA ----
#pragma unroll
    for (int L = 0; L < 3; ++L) {
        unsigned w0a[8], w1a[8];
#pragma unroll
        for (int j = 0; j < 8; ++j) {
            {
                float x0 = acc0[2 * j], x1 = acc0[2 * j + 1];
                float s0 = __sinf(x0), s1 = __sinf(x1);
                w0a[j] = pkrtz(fmaf(0.5f, x0, s0 * s0), fmaf(0.5f, x1, s1 * s1));
            }
            {
                float x0 = acc1[2 * j], x1 = acc1[2 * j + 1];
                float s0 = __sinf(x0), s1 = __sinf(x1);
                w1a[j] = pkrtz(fmaf(0.5f, x0, s0 * s0), fmaf(0.5f, x1, s1 * s1));
            }
        }
        PSWAP(w0a[0], w0a[2]); PSWAP(w0a[1], w0a[3]);
        PSWAP(w0a[4], w0a[6]); PSWAP(w0a[5], w0a[7]);
        PSWAP(w1a[0], w1a[2]); PSWAP(w1a[1], w1a[3]);
        PSWAP(w1a[4], w1a[6]); PSWAP(w1a[5], w1a[7]);

        f32x16 cb;                          // bias into C operand
#pragma unroll
        for (int r = 0; r < 16; ++r) {
            int nr = (r & 3) + 8 * (r >> 2) + 4 * H;
            cb[r] = bh[L * NHID + nr];
        }
        half8 ah0, ah1;
        {
            float e[8];
#pragma unroll
            for (int i = 0; i < 8; ++i) e[i] = Wh[(L * NHID + H * 8 + i) * NHID + nn];
            ah0 = mk8(pkrtz(e[0], e[1]), pkrtz(e[2], e[3]),
                      pkrtz(e[4], e[5]), pkrtz(e[6], e[7]));
        }
        {
            float e[8];
#pragma unroll
            for (int i = 0; i < 8; ++i) e[i] = Wh[(L * NHID + 16 + H * 8 + i) * NHID + nn];
            ah1 = mk8(pkrtz(e[0], e[1]), pkrtz(e[2], e[3]),
                      pkrtz(e[4], e[5]), pkrtz(e[6], e[7]));
        }
        acc0 = MF(ah1, mk8(w0a[4], w0a[5], w0a[6], w0a[7]),
                  MF(ah0, mk8(w0a[0], w0a[1], w0a[2], w0a[3]), cb));
        acc1 = MF(ah1, mk8(w1a[4], w1a[5], w1a[6], w1a[7]),
                  MF(ah0, mk8(w1a[0], w1a[1], w1a[2], w1a[3]), cb));
    }

    // ---- final layer: snake -> dot(Wf) -> cross-half reduce ----
    float t0 = 0.0f, t1 = 0.0f;
#pragma unroll
    for (int r = 0; r < 16; ++r) {
        int nr = (r & 3) + 8 * (r >> 2) + 4 * H;
        float wf = Wf[nr];
        { float x = acc0[r]; float s = __sinf(x); t0 = fmaf(fmaf(0.5f, x, s * s), wf, t0); }
        { float x = acc1[r]; float s = __sinf(x); t1 = fmaf(fmaf(0.5f, x, s * s), wf, t1); }
    }
    t0 += __shfl_xor(t0, 32);
    t1 += __shfl_xor(t1, 32);
    float res = (H ? t1 : t0) + bf[0];
    if (p < n) out[p] = res;
}

// ---- fallback (ws too small): scalar fp32 path, channels-first grid ----
__global__ __launch_bounds__(256) void fgm_scalar(
    const float* __restrict__ coords, const float* __restrict__ grid,
    const float* __restrict__ W0, const float* __restrict__ b0,
    const float* __restrict__ Wh, const float* __restrict__ bh,
    const float* __restrict__ Wf, const float* __restrict__ bf,
    float* __restrict__ out, int n)
{
    int i = blockIdx.x * blockDim.x + threadIdx.x;
    if (i >= n) return;
    float cx = coords[3 * i + 0], cy = coords[3 * i + 1], cz = coords[3 * i + 2];
    float fx = (cx + 1.0f) * (NG * 0.5f) - 0.5f;
    float fy = (cy + 1.0f) * (NG * 0.5f) - 0.5f;
    float fz = (cz + 1.0f) * (NG * 0.5f) - 0.5f;
    float flx = floorf(fx), fly = floorf(fy), flz = floorf(fz);
    float wx = fx - flx, wy = fy - fly, wz = fz - flz;
    int ix0 = (int)flx, iy0 = (int)fly, iz0 = (int)flz;
    float fv[NC];
#pragma unroll
    for (int c = 0; c < NC; ++c) fv[c] = 0.0f;
    float wxs[2] = {1.0f - wx, wx}, wys[2] = {1.0f - wy, wy}, wzs[2] = {1.0f - wz, wz};
#pragma unroll
    for (int dz = 0; dz < 2; ++dz) {
        int zi = iz0 + dz; bool vz = (zi >= 0) && (zi < NG);
        int zc = min(max(zi, 0), NG - 1);
#pragma unroll
        for (int dy = 0; dy < 2; ++dy) {
            int yi = iy0 + dy; bool vy = (yi >= 0) && (yi < NG);
            int yc = min(max(yi, 0), NG - 1);
#pragma unroll
            for (int dx = 0; dx < 2; ++dx) {
                int xi = ix0 + dx; bool vx = (xi >= 0) && (xi < NG);
                int xc = min(max(xi, 0), NG - 1);
                float w = wzs[dz] * wys[dy] * wxs[dx];
                w = (vx && vy && vz) ? w : 0.0f;
                int off = ((zc * NG) + yc) * NG + xc;
#pragma unroll
                for (int c = 0; c < NC; ++c)
                    fv[c] = fmaf(w, grid[c * NVOX + off], fv[c]);
            }
        }
    }
    float h[NHID];
#pragma unroll
    for (int j = 0; j < NHID; ++j) h[j] = b0[j];
#pragma unroll
    for (int j = 0; j < NHID; ++j) h[j] = fmaf(cx, W0[0 * NHID + j], h[j]);
#pragma unroll
    for (int j = 0; j < NHID; ++j) h[j] = fmaf(cy, W0[1 * NHID + j], h[j]);
#pragma unroll
    for (int j = 0; j < NHID; ++j) h[j] = fmaf(cz, W0[2 * NHID + j], h[j]);
#pragma unroll
    for (int l = 0; l < NL; ++l) {
        float fs = (float)(1 << l);
        float sv[6];
        sv[0] = __sinf(cx * fs); sv[1] = __sinf(cy * fs); sv[2] = __sinf(cz * fs);
        sv[3] = __cosf(cx * fs); sv[4] = __cosf(cy * fs); sv[5] = __cosf(cz * fs);
#pragma unroll
        for (int r = 0; r < 6; ++r) {
            const float* wr = W0 + (size_t)(3 + 6 * l + r) * NHID;
            float a = sv[r];
#pragma unroll
            for (int j = 0; j < NHID; ++j) h[j] = fmaf(a, wr[j], h[j]);
        }
    }
#pragma unroll
    for (int r = 0; r < NC; ++r) {
        const float* wr = W0 + (size_t)(3 + 6 * NL + r) * NHID;
        float a = fv[r];
#pragma unroll
        for (int j = 0; j < NHID; ++j) h[j] = fmaf(a, wr[j], h[j]);
    }
    float act[NHID];
#pragma unroll
    for (int layer = 0; layer < 3; ++layer) {
#pragma unroll
        for (int j = 0; j < NHID; ++j) {
            float s = __sinf(h[j]);
            act[j] = fmaf(0.5f, h[j], s * s);
        }
#pragma unroll
        for (int j = 0; j < NHID; ++j) h[j] = bh[layer * NHID + j];
#pragma unroll
        for (int r = 0; r < NHID; ++r) {
            const float* wr = Wh + (size_t)(layer * NHID + r) * NHID;
            float a = act[r];
#pragma unroll
            for (int j = 0; j < NHID; ++j) h[j] = fmaf(a, wr[j], h[j]);
        }
    }
    float acc = bf[0];
#pragma unroll
    for (int j = 0; j < NHID; ++j) {
        float s = __sinf(h[j]);
        acc = fmaf(fmaf(0.5f, h[j], s * s), Wf[j], acc);
    }
    out[i] = acc;
}

extern "C" void kernel_launch(void* const* d_in, const int* in_sizes, int n_in,
                              void* d_out, int out_size, void* d_ws, size_t ws_size,
                              hipStream_t stream)
{
    const float* coords = (const float*)d_in[0];
    const float* grid   = (const float*)d_in[1];
    const float* W0     = (const float*)d_in[2];
    const float* b0     = (const float*)d_in[3];
    const float* Wh     = (const float*)d_in[4];
    const float* bh     = (const float*)d_in[5];
    const float* Wf     = (const float*)d_in[6];
    const float* bf     = (const float*)d_in[7];
    float* out = (float*)d_out;
    int n = in_sizes[0] / 3;

    size_t needed = (size_t)NVOX * 16;   // 4 MiB fp8 grid
    if (ws_size >= needed) {
        uint4* g8 = (uint4*)d_ws;
        grid_to_fp8<<<(NVOX + 255) / 256, 256, 0, stream>>>(grid, g8);
        fgm_mfma<<<(n + 255) / 256, 256, 0, stream>>>(
            coords, g8, W0, b0, Wh, bh, Wf, bf, out, n);
    } else {
        fgm_scalar<<<(n + 255) / 256, 256, 0, stream>>>(
            coords, grid, W0, b0, Wh, bh, Wf, bf, out, n);
    }
}

// Round 7
// 65.481 us; speedup vs baseline: 2.8150x; 1.2413x over previous
//
#include <hip/hip_runtime.h>
#include <hip/hip_fp16.h>

#define NG 64
#define NVOX (NG*NG*NG)
#define NC 16
#define NHID 32
#define NL 10

typedef _Float16 half8 __attribute__((ext_vector_type(8)));
typedef __fp16   fp16x2 __attribute__((ext_vector_type(2)));
typedef float f32x16 __attribute__((ext_vector_type(16)));
typedef float f32x2 __attribute__((ext_vector_type(2)));

union U32H2 { unsigned u; fp16x2 h; __half2 hh; };

__device__ __forceinline__ unsigned pkrtz(float a, float b) {
    U32H2 t; t.h = __builtin_amdgcn_cvt_pkrtz(a, b); return t.u;
}
__device__ __forceinline__ half8 mk8(unsigned a, unsigned b, unsigned c, unsigned d) {
    union { unsigned u[4]; half8 v; } r;
    r.u[0] = a; r.u[1] = b; r.u[2] = c; r.u[3] = d; return r.v;
}
__device__ __forceinline__ f32x16 MF(half8 a, half8 b, f32x16 c) {
    return __builtin_amdgcn_mfma_f32_32x32x16_f16(a, b, c, 0, 0, 0);
}
// v_permlane32_swap_b32 a,b : a <- [a_lo | b_lo], b <- [a_hi | b_hi]
#define PSWAP(a, b) asm volatile("v_permlane32_swap_b32 %0, %1" : "+v"(a), "+v"(b))

// ---- pass 1: grid (C,D,H,W) f32 -> voxel-major fp8 e4m3 (D,H,W,C), 4 MiB ----
__global__ __launch_bounds__(256) void grid_to_fp8(const float* __restrict__ in,
                                                   uint4* __restrict__ out)
{
    int v = blockIdx.x * 256 + threadIdx.x;
    if (v >= NVOX) return;
    unsigned o[4];
#pragma unroll
    for (int c = 0; c < 4; ++c) {
        float f0 = in[(4 * c + 0) * NVOX + v];
        float f1 = in[(4 * c + 1) * NVOX + v];
        float f2 = in[(4 * c + 2) * NVOX + v];
        float f3 = in[(4 * c + 3) * NVOX + v];
        int w = 0;
        w = __builtin_amdgcn_cvt_pk_fp8_f32(f0, f1, w, false);  // bytes 0,1
        w = __builtin_amdgcn_cvt_pk_fp8_f32(f2, f3, w, true);   // bytes 2,3
        o[c] = (unsigned)w;
    }
    out[v] = make_uint4(o[0], o[1], o[2], o[3]);
}

// ---- pass 2: fused grid-sample + PE + 4-layer MLP, f16 MFMA, ZERO LDS ----
// Wave = 64 points = 2 MFMA m-tiles of 32. x layout (k-permuted, 80 rows):
// k0..1=cx,cy  k2=cz  k3=1(bias row->b0)  k4..63=PE  k64..79=feats.
// Layer-0 B-fragments built from per-lane xr[] via permlane32_swap:
//   PSWAP(xr[8s+j], xr[8s+4+j]) -> (bw0[j], bw1[j]) for both tiles at once.
// D: col=lane&31, row=(r&3)+8*(r>>2)+4*(lane>>5).
__global__ __launch_bounds__(256, 4) void fgm_mfma(
    const float* __restrict__ coords, const uint4* __restrict__ grid8,
    const float* __restrict__ W0, const float* __restrict__ b0,
    const float* __restrict__ Wh, const float* __restrict__ bh,
    const float* __restrict__ Wf, const float* __restrict__ bf,
    float* __restrict__ out, int n)
{
    const int lane = threadIdx.x & 63;
    const int wid  = threadIdx.x >> 6;
    const int base = blockIdx.x * 256 + wid * 64;
    if (base >= n) return;
    const int p  = base + lane;
    const int pc = min(p, n - 1);
    const int H  = lane >> 5;
    const int nn = lane & 31;

    float cx = coords[3 * pc + 0], cy = coords[3 * pc + 1], cz = coords[3 * pc + 2];

    // ---- trilinear grid sample, fp8 grid -> f32 accumulate ----
    float fx = (cx + 1.0f) * (NG * 0.5f) - 0.5f;
    float fy = (cy + 1.0f) * (NG * 0.5f) - 0.5f;
    float fz = (cz + 1.0f) * (NG * 0.5f) - 0.5f;
    float flx = floorf(fx), fly = floorf(fy), flz = floorf(fz);
    float wx = fx - flx, wy = fy - fly, wz = fz - flz;
    int ix0 = (int)flx, iy0 = (int)fly, iz0 = (int)flz;
    float wxs[2] = {1.0f - wx, wx}, wys[2] = {1.0f - wy, wy}, wzs[2] = {1.0f - wz, wz};

    float fv[NC];
#pragma unroll
    for (int c = 0; c < NC; ++c) fv[c] = 0.0f;

#pragma unroll
    for (int dz = 0; dz < 2; ++dz) {
        int zi = iz0 + dz; bool vz = (zi >= 0) && (zi < NG);
        int zc = min(max(zi, 0), NG - 1);
#pragma unroll
        for (int dy = 0; dy < 2; ++dy) {
            int yi = iy0 + dy; bool vy = (yi >= 0) && (yi < NG);
            int yc = min(max(yi, 0), NG - 1);
#pragma unroll
            for (int dx = 0; dx < 2; ++dx) {
                int xi = ix0 + dx; bool vx = (xi >= 0) && (xi < NG);
                int xc = min(max(xi, 0), NG - 1);
                float w = wzs[dz] * wys[dy] * wxs[dx];
                w = (vx && vy && vz) ? w : 0.0f;
                uint4 q = grid8[((zc * NG) + yc) * NG + xc];
                f32x2 d;
                d = __builtin_amdgcn_cvt_pk_f32_fp8((int)q.x, false);
                fv[0]  = fmaf(w, d.x, fv[0]);  fv[1]  = fmaf(w, d.y, fv[1]);
                d = __builtin_amdgcn_cvt_pk_f32_fp8((int)q.x, true);
                fv[2]  = fmaf(w, d.x, fv[2]);  fv[3]  = fmaf(w, d.y, fv[3]);
                d = __builtin_amdgcn_cvt_pk_f32_fp8((int)q.y, false);
                fv[4]  = fmaf(w, d.x, fv[4]);  fv[5]  = fmaf(w, d.y, fv[5]);
                d = __builtin_amdgcn_cvt_pk_f32_fp8((int)q.y, true);
                fv[6]  = fmaf(w, d.x, fv[6]);  fv[7]  = fmaf(w, d.y, fv[7]);
                d = __builtin_amdgcn_cvt_pk_f32_fp8((int)q.z, false);
                fv[8]  = fmaf(w, d.x, fv[8]);  fv[9]  = fmaf(w, d.y, fv[9]);
                d = __builtin_amdgcn_cvt_pk_f32_fp8((int)q.z, true);
                fv[10] = fmaf(w, d.x, fv[10]); fv[11] = fmaf(w, d.y, fv[11]);
                d = __builtin_amdgcn_cvt_pk_f32_fp8((int)q.w, false);
                fv[12] = fmaf(w, d.x, fv[12]); fv[13] = fmaf(w, d.y, fv[13]);
                d = __builtin_amdgcn_cvt_pk_f32_fp8((int)q.w, true);
                fv[14] = fmaf(w, d.x, fv[14]); fv[15] = fmaf(w, d.y, fv[15]);
            }
        }
    }

    // ---- x (f16 pairs) in registers ----
    unsigned xr[40];
    xr[0] = pkrtz(cx, cy);
    xr[1] = pkrtz(cz, 1.0f);      // k=3: bias row input = 1
#pragma unroll
    for (int l0 = 0; l0 < NL; ++l0) {
        float f = (float)(1 << l0);
        float sx, cax, sy, cay, sz, caz;
        __sincosf(cx * f, &sx, &cax);
        __sincosf(cy * f, &sy, &cay);
        __sincosf(cz * f, &sz, &caz);
        xr[2 + 3 * l0 + 0] = pkrtz(sx, sy);
        xr[2 + 3 * l0 + 1] = pkrtz(sz, cax);
        xr[2 + 3 * l0 + 2] = pkrtz(cay, caz);
    }
#pragma unroll
    for (int j = 0; j < 8; ++j)
        xr[32 + j] = pkrtz(fv[2 * j], fv[2 * j + 1]);

    // ---- A-fragments for layer 0 (k-permuted W0 rows; k=3 is the bias row) ----
    half8 a0[5];
#pragma unroll
    for (int s = 0; s < 5; ++s) {
        float e[8];
#pragma unroll
        for (int i = 0; i < 8; ++i) {
            const int k0 = s * 16 + i;
            const float* q0 = (k0 == 3) ? (b0 + nn)
                             : (W0 + (k0 - (k0 >= 4 ? 1 : 0)) * NHID + nn);
            const float* q1 = W0 + (k0 + 8 - 1) * NHID + nn;   // k1>=8, never bias
            e[i] = *(H ? q1 : q0);
        }
        a0[s] = mk8(pkrtz(e[0], e[1]), pkrtz(e[2], e[3]),
                    pkrtz(e[4], e[5]), pkrtz(e[6], e[7]));
    }

    // ---- layer-0 B-fragments via permlane32_swap (in place on xr) ----
#pragma unroll
    for (int s = 0; s < 5; ++s) {
        PSWAP(xr[8 * s + 0], xr[8 * s + 4]);
        PSWAP(xr[8 * s + 1], xr[8 * s + 5]);
        PSWAP(xr[8 * s + 2], xr[8 * s + 6]);
        PSWAP(xr[8 * s + 3], xr[8 * s + 7]);
    }

    // ---- layer 0: 5 K-slices x 2 tiles ----
    f32x16 acc0, acc1;
#pragma unroll
    for (int r = 0; r < 16; ++r) { acc0[r] = 0.0f; acc1[r] = 0.0f; }
#pragma unroll
    for (int s = 0; s < 5; ++s) {
        acc0 = MF(a0[s], mk8(xr[8*s+0], xr[8*s+1], xr[8*s+2], xr[8*s+3]), acc0);
        acc1 = MF(a0[s], mk8(xr[8*s+4], xr[8*s+5], xr[8*s+6], xr[8*s+7]), acc1);
    }

    // ---- hidden layers: snake -> f16 pairs -> permlane B-frags -> MFMA ----
#pragma unroll
    for (int L = 0; L < 3; ++L) {
        unsigned w0a[8], w1a[8];
#pragma unroll
        for (int j = 0; j < 8; ++j) {
            {
                float x0 = acc0[2 * j], x1 = acc0[2 * j + 1];
                float s0 = __sinf(x0), s1 = __sinf(x1);
                w0a[j] = pkrtz(fmaf(0.5f, x0, s0 * s0), fmaf(0.5f, x1, s1 * s1));
            }
            {
                float x0 = acc1[2 * j], x1 = acc1[2 * j + 1];
                float s0 = __sinf(x0), s1 = __sinf(x1);
                w1a[j] = pkrtz(fmaf(0.5f, x0, s0 * s0), fmaf(0.5f, x1, s1 * s1));
            }
        }
        PSWAP(w0a[0], w0a[2]); PSWAP(w0a[1], w0a[3]);
        PSWAP(w0a[4], w0a[6]); PSWAP(w0a[5], w0a[7]);
        PSWAP(w1a[0], w1a[2]); PSWAP(w1a[1], w1a[3]);
        PSWAP(w1a[4], w1a[6]); PSWAP(w1a[5], w1a[7]);

        f32x16 cb;                          // bias into C operand
#pragma unroll
        for (int r = 0; r < 16; ++r) {
            int nr = (r & 3) + 8 * (r >> 2) + 4 * H;
            cb[r] = bh[L * NHID + nr];
        }
        half8 ah0, ah1;
        {
            float e[8];
#pragma unroll
            for (int i = 0; i < 8; ++i) e[i] = Wh[(L * NHID + H * 8 + i) * NHID + nn];
            ah0 = mk8(pkrtz(e[0], e[1]), pkrtz(e[2], e[3]),
                      pkrtz(e[4], e[5]), pkrtz(e[6], e[7]));
        }
        {
            float e[8];
#pragma unroll
            for (int i = 0; i < 8; ++i) e[i] = Wh[(L * NHID + 16 + H * 8 + i) * NHID + nn];
            ah1 = mk8(pkrtz(e[0], e[1]), pkrtz(e[2], e[3]),
                      pkrtz(e[4], e[5]), pkrtz(e[6], e[7]));
        }
        acc0 = MF(ah1, mk8(w0a[4], w0a[5], w0a[6], w0a[7]),
                  MF(ah0, mk8(w0a[0], w0a[1], w0a[2], w0a[3]), cb));
        acc1 = MF(ah1, mk8(w1a[4], w1a[5], w1a[6], w1a[7]),
                  MF(ah0, mk8(w1a[0], w1a[1], w1a[2], w1a[3]), cb));
    }

    // ---- final layer: snake -> dot(Wf) -> cross-half reduce ----
    float t0 = 0.0f, t1 = 0.0f;
#pragma unroll
    for (int r = 0; r < 16; ++r) {
        int nr = (r & 3) + 8 * (r >> 2) + 4 * H;
        float wf = Wf[nr];
        { float x = acc0[r]; float s = __sinf(x); t0 = fmaf(fmaf(0.5f, x, s * s), wf, t0); }
        { float x = acc1[r]; float s = __sinf(x); t1 = fmaf(fmaf(0.5f, x, s * s), wf, t1); }
    }
    t0 += __shfl_xor(t0, 32);
    t1 += __shfl_xor(t1, 32);
    float res = (H ? t1 : t0) + bf[0];
    if (p < n) out[p] = res;
}

// ---- fallback (ws too small): scalar fp32 path, channels-first grid ----
__global__ __launch_bounds__(256) void fgm_scalar(
    const float* __restrict__ coords, const float* __restrict__ grid,
    const float* __restrict__ W0, const float* __restrict__ b0,
    const float* __restrict__ Wh, const float* __restrict__ bh,
    const float* __restrict__ Wf, const float* __restrict__ bf,
    float* __restrict__ out, int n)
{
    int i = blockIdx.x * blockDim.x + threadIdx.x;
    if (i >= n) return;
    float cx = coords[3 * i + 0], cy = coords[3 * i + 1], cz = coords[3 * i + 2];
    float fx = (cx + 1.0f) * (NG * 0.5f) - 0.5f;
    float fy = (cy + 1.0f) * (NG * 0.5f) - 0.5f;
    float fz = (cz + 1.0f) * (NG * 0.5f) - 0.5f;
    float flx = floorf(fx), fly = floorf(fy), flz = floorf(fz);
    float wx = fx - flx, wy = fy - fly, wz = fz - flz;
    int ix0 = (int)flx, iy0 = (int)fly, iz0 = (int)flz;
    float fv[NC];
#pragma unroll
    for (int c = 0; c < NC; ++c) fv[c] = 0.0f;
    float wxs[2] = {1.0f - wx, wx}, wys[2] = {1.0f - wy, wy}, wzs[2] = {1.0f - wz, wz};
#pragma unroll
    for (int dz = 0; dz < 2; ++dz) {
        int zi = iz0 + dz; bool vz = (zi >= 0) && (zi < NG);
        int zc = min(max(zi, 0), NG - 1);
#pragma unroll
        for (int dy = 0; dy < 2; ++dy) {
            int yi = iy0 + dy; bool vy = (yi >= 0) && (yi < NG);
            int yc = min(max(yi, 0), NG - 1);
#pragma unroll
            for (int dx = 0; dx < 2; ++dx) {
                int xi = ix0 + dx; bool vx = (xi >= 0) && (xi < NG);
                int xc = min(max(xi, 0), NG - 1);
                float w = wzs[dz] * wys[dy] * wxs[dx];
                w = (vx && vy && vz) ? w : 0.0f;
                int off = ((zc * NG) + yc) * NG + xc;
#pragma unroll
                for (int c = 0; c < NC; ++c)
                    fv[c] = fmaf(w, grid[c * NVOX + off], fv[c]);
            }
        }
    }
    float h[NHID];
#pragma unroll
    for (int j = 0; j < NHID; ++j) h[j] = b0[j];
#pragma unroll
    for (int j = 0; j < NHID; ++j) h[j] = fmaf(cx, W0[0 * NHID + j], h[j]);
#pragma unroll
    for (int j = 0; j < NHID; ++j) h[j] = fmaf(cy, W0[1 * NHID + j], h[j]);
#pragma unroll
    for (int j = 0; j < NHID; ++j) h[j] = fmaf(cz, W0[2 * NHID + j], h[j]);
#pragma unroll
    for (int l = 0; l < NL; ++l) {
        float fs = (float)(1 << l);
        float sv[6];
        sv[0] = __sinf(cx * fs); sv[1] = __sinf(cy * fs); sv[2] = __sinf(cz * fs);
        sv[3] = __cosf(cx * fs); sv[4] = __cosf(cy * fs); sv[5] = __cosf(cz * fs);
#pragma unroll
        for (int r = 0; r < 6; ++r) {
            const float* wr = W0 + (size_t)(3 + 6 * l + r) * NHID;
            float a = sv[r];
#pragma unroll
            for (int j = 0; j < NHID; ++j) h[j] = fmaf(a, wr[j], h[j]);
        }
    }
#pragma unroll
    for (int r = 0; r < NC; ++r) {
        const float* wr = W0 + (size_t)(3 + 6 * NL + r) * NHID;
        float a = fv[r];
#pragma unroll
        for (int j = 0; j < NHID; ++j) h[j] = fmaf(a, wr[j], h[j]);
    }
    float act[NHID];
#pragma unroll
    for (int layer = 0; layer < 3; ++layer) {
#pragma unroll
        for (int j = 0; j < NHID; ++j) {
            float s = __sinf(h[j]);
            act[j] = fmaf(0.5f, h[j], s * s);
        }
#pragma unroll
        for (int j = 0; j < NHID; ++j) h[j] = bh[layer * NHID + j];
#pragma unroll
        for (int r = 0; r < NHID; ++r) {
            const float* wr = Wh + (size_t)(layer * NHID + r) * NHID;
            float a = act[r];
#pragma unroll
            for (int j = 0; j < NHID; ++j) h[j] = fmaf(a, wr[j], h[j]);
        }
    }
    float acc = bf[0];
#pragma unroll
    for (int j = 0; j < NHID; ++j) {
        float s = __sinf(h[j]);
        acc = fmaf(fmaf(0.5f, h[j], s * s), Wf[j], acc);
    }
    out[i] = acc;
}

extern "C" void kernel_launch(void* const* d_in, const int* in_sizes, int n_in,
                              void* d_out, int out_size, void* d_ws, size_t ws_size,
                              hipStream_t stream)
{
    const float* coords = (const float*)d_in[0];
    const float* grid   = (const float*)d_in[1];
    const float* W0     = (const float*)d_in[2];
    const float* b0     = (const float*)d_in[3];
    const float* Wh     = (const float*)d_in[4];
    const float* bh     = (const float*)d_in[5];
    const float* Wf     = (const float*)d_in[6];
    const float* bf     = (const float*)d_in[7];
    float* out = (float*)d_out;
    int n = in_sizes[0] / 3;

    size_t needed = (size_t)NVOX * 16;   // 4 MiB fp8 grid
    if (ws_size >= needed) {
        uint4* g8 = (uint4*)d_ws;
        grid_to_fp8<<<(NVOX + 255) / 256, 256, 0, stream>>>(grid, g8);
        fgm_mfma<<<(n + 255) / 256, 256, 0, stream>>>(
            coords, g8, W0, b0, Wh, bh, Wf, bf, out, n);
    } else {
        fgm_scalar<<<(n + 255) / 256, 256, 0, stream>>>(
            coords, grid, W0, b0, Wh, bh, Wf, bf, out, n);
    }
}